// Round 3
// baseline (529.029 us; speedup 1.0000x reference)
//
#include <hip/hip_runtime.h>

// GridPoolingLayer: per-cell mean pooling; cells are rectangles from rising
// edges of h_mask/v_mask. H=W=768, C=64, fp32.
//
// R3: one wave per cell with DYNAMIC queue (atomicAdd pops of 2 cells) to
// kill the static-assignment tail, + flat-pixel lane mapping for narrow
// cells (wdt<4) so all 64 lanes stay busy, + 2-deep unroll on wide cells.

#define GH 768
#define GW 768
#define MAXSEG 385  // alternating mask gives 384 rising edges -> 385 segments

enum {
    OFF_ROWSTART = 0,
    OFF_ROWEND   = OFF_ROWSTART + MAXSEG,
    OFF_COLSTART = OFF_ROWEND + MAXSEG,
    OFF_COLEND   = OFF_COLSTART + MAXSEG,
    OFF_NROWS    = OFF_COLEND + MAXSEG,
    OFF_NCOLS    = OFF_NROWS + 1,
    OFF_QHEAD    = OFF_NCOLS + 1,
};

__device__ __forceinline__ void acc4(float4& a, const float4 v) {
    a.x += v.x; a.y += v.y; a.z += v.z; a.w += v.w;
}

__global__ __launch_bounds__(768) void seg_scan(const int* __restrict__ h_mask,
                                                const int* __restrict__ v_mask,
                                                int* __restrict__ ws) {
    __shared__ int s[GH];
    const int i = threadIdx.x;
    const bool is_row = (blockIdx.x == 0);
    const int* m = is_row ? h_mask : v_mask;

    int mi = m[i];
    int rising = 0;
    if (i > 0) rising = (mi == 1 && m[i - 1] == 0) ? 1 : 0;  // rising[0] forced 0
    s[i] = rising;
    __syncthreads();

    for (int off = 1; off < GH; off <<= 1) {
        int add = (i >= off) ? s[i - off] : 0;
        __syncthreads();
        s[i] += add;
        __syncthreads();
    }

    const int seg  = s[i];
    const int segL = (i == 0)      ? -1 : s[i - 1];
    const int segR = (i == GH - 1) ? -2 : s[i + 1];

    int* start = ws + (is_row ? OFF_ROWSTART : OFF_COLSTART);
    int* end   = ws + (is_row ? OFF_ROWEND   : OFF_COLEND);
    if (seg != segL) start[seg] = i;
    if (seg != segR) end[seg]   = i + 1;
    if (i == GH - 1) ws[is_row ? OFF_NROWS : OFF_NCOLS] = seg + 1;
    if (i == 0 && is_row) ws[OFF_QHEAD] = 0;  // init work queue
}

__global__ __launch_bounds__(256) void cell_pool(const float4* __restrict__ in,
                                                 float4* __restrict__ out,
                                                 int* __restrict__ ws) {
    const int nrows  = ws[OFF_NROWS];
    const int ncols  = ws[OFF_NCOLS];
    const int ncells = nrows * ncols;

    const int lane = threadIdx.x & 63;
    const int pg   = lane >> 4;   // pixel slot within quad
    const int cq   = lane & 15;   // channel quad: floats 4*cq .. 4*cq+3

    for (;;) {
        int c0 = 0;
        if (lane == 0) c0 = atomicAdd(ws + OFF_QHEAD, 2);
        c0 = __shfl(c0, 0, 64);
        if (c0 >= ncells) break;
        const int cend = (c0 + 2 < ncells) ? c0 + 2 : ncells;

        for (int cell = c0; cell < cend; ++cell) {
            const int br = cell / ncols;
            const int bc = cell - br * ncols;
            const int y0 = ws[OFF_ROWSTART + br];
            const int y1 = ws[OFF_ROWEND + br];
            const int x0 = ws[OFF_COLSTART + bc];
            const int x1 = ws[OFF_COLEND + bc];
            const int h   = y1 - y0;
            const int wdt = x1 - x0;
            const int npx = h * wdt;

            float4 a0 = make_float4(0.f, 0.f, 0.f, 0.f);
            float4 a1 = make_float4(0.f, 0.f, 0.f, 0.f);

            if (wdt >= 4) {
                for (int y = y0; y < y1; ++y) {
                    const size_t rb = (size_t)(y * GW) * 16 + cq;
                    int x = x0 + pg;
                    for (; x + 4 < x1; x += 8) {
                        float4 v0 = in[rb + (size_t)x * 16];
                        float4 v1 = in[rb + (size_t)(x + 4) * 16];
                        acc4(a0, v0);
                        acc4(a1, v1);
                    }
                    for (; x < x1; x += 4) acc4(a0, in[rb + (size_t)x * 16]);
                }
            } else {
                // narrow cell: flatten pixels so all 4 pg slots stay busy
                for (int base = 0; base < npx; base += 4) {
                    const int p = base + pg;
                    if (p < npx) {
                        const int yy = p / wdt;
                        const int xx = p - yy * wdt;
                        acc4(a0, in[((size_t)((y0 + yy) * GW + x0 + xx)) * 16 + cq]);
                    }
                }
            }
            acc4(a0, a1);
            #pragma unroll
            for (int msk = 16; msk < 64; msk <<= 1) {
                a0.x += __shfl_xor(a0.x, msk, 64);
                a0.y += __shfl_xor(a0.y, msk, 64);
                a0.z += __shfl_xor(a0.z, msk, 64);
                a0.w += __shfl_xor(a0.w, msk, 64);
            }
            const float area = (float)npx;  // >= 1 always
            float4 mean;
            mean.x = a0.x / area; mean.y = a0.y / area;
            mean.z = a0.z / area; mean.w = a0.w / area;

            if (wdt >= 4) {
                for (int y = y0; y < y1; ++y) {
                    const size_t rb = (size_t)(y * GW) * 16 + cq;
                    for (int x = x0 + pg; x < x1; x += 4)
                        out[rb + (size_t)x * 16] = mean;
                }
            } else {
                for (int base = 0; base < npx; base += 4) {
                    const int p = base + pg;
                    if (p < npx) {
                        const int yy = p / wdt;
                        const int xx = p - yy * wdt;
                        out[((size_t)((y0 + yy) * GW + x0 + xx)) * 16 + cq] = mean;
                    }
                }
            }
        }
    }
}

extern "C" void kernel_launch(void* const* d_in, const int* in_sizes, int n_in,
                              void* d_out, int out_size, void* d_ws, size_t ws_size,
                              hipStream_t stream) {
    const float* in  = (const float*)d_in[0];   // [1,768,768,64] fp32
    const int* hmask = (const int*)d_in[1];     // [1,768] int32
    const int* vmask = (const int*)d_in[2];     // [1,768] int32
    float* out = (float*)d_out;                 // [1,768,768,64] fp32
    int* ws = (int*)d_ws;

    seg_scan<<<2, GH, 0, stream>>>(hmask, vmask, ws);
    // 2048 blocks x 4 waves = 8192 persistent waves (32 waves/CU at 256 CUs)
    cell_pool<<<2048, 256, 0, stream>>>((const float4*)in, (float4*)out, ws);
}

// Round 4
// 291.077 us; speedup vs baseline: 1.8175x; 1.8175x over previous
//
#include <hip/hip_runtime.h>

// GridPoolingLayer: per-cell mean pooling; cells are rectangles from rising
// edges of h_mask/v_mask. H=W=768, C=64, fp32.
//
// R4: SEPARABLE three-pass decomposition (no per-cell waves, no atomics):
//   A col_sum : thread per (row_seg, x, chquad): sum over the segment's rows.
//               Perfectly balanced (uniform height within each wave),
//               coalesced 1KB/wave loads. colsum lives in d_out (scratch).
//   B cell_mean: thread per (row_seg, col_seg, chquad): sum colsum over the
//               col segment, divide by area -> mean, in d_ws.
//   C bcast   : thread per output float4: out = mean[rid[y]][cid[x]][cq].
//               Pure coalesced write; mean is L2/L3-resident.
// Fallback to the R2 static wave-per-cell kernel if ws_size < ~38 MB.

#define GH 768
#define GW 768
#define MAXSEG 385  // alternating mask gives 384 rising edges -> 385 segments
#define ROWQ (GW * 16)  // float4 units per row segment = 768*16 = 12288

enum {
    OFF_ROWSTART = 0,
    OFF_ROWEND   = OFF_ROWSTART + MAXSEG,
    OFF_COLSTART = OFF_ROWEND + MAXSEG,
    OFF_COLEND   = OFF_COLSTART + MAXSEG,
    OFF_NROWS    = OFF_COLEND + MAXSEG,
    OFF_NCOLS    = OFF_NROWS + 1,
    OFF_RID      = OFF_NCOLS + 3,   // 768 per-pixel row segment ids
    OFF_CID      = OFF_RID + GH,    // 768 per-pixel col segment ids
    OFF_END      = OFF_CID + GW,
};
#define MEAN_OFF_BYTES 16384                       // mean array starts here in ws
#define MEAN_CAP_BYTES ((size_t)MAXSEG * MAXSEG * 64 * 4)  // 37.95 MB worst case

__device__ __forceinline__ void acc4(float4& a, const float4 v) {
    a.x += v.x; a.y += v.y; a.z += v.z; a.w += v.w;
}

__global__ __launch_bounds__(768) void seg_scan(const int* __restrict__ h_mask,
                                                const int* __restrict__ v_mask,
                                                int* __restrict__ ws) {
    __shared__ int s[GH];
    const int i = threadIdx.x;
    const bool is_row = (blockIdx.x == 0);
    const int* m = is_row ? h_mask : v_mask;

    int mi = m[i];
    int rising = 0;
    if (i > 0) rising = (mi == 1 && m[i - 1] == 0) ? 1 : 0;  // rising[0] forced 0
    s[i] = rising;
    __syncthreads();

    for (int off = 1; off < GH; off <<= 1) {
        int add = (i >= off) ? s[i - off] : 0;
        __syncthreads();
        s[i] += add;
        __syncthreads();
    }

    const int seg  = s[i];
    const int segL = (i == 0)      ? -1 : s[i - 1];
    const int segR = (i == GH - 1) ? -2 : s[i + 1];

    int* start = ws + (is_row ? OFF_ROWSTART : OFF_COLSTART);
    int* end   = ws + (is_row ? OFF_ROWEND   : OFF_COLEND);
    if (seg != segL) start[seg] = i;
    if (seg != segR) end[seg]   = i + 1;
    ws[(is_row ? OFF_RID : OFF_CID) + i] = seg;  // per-pixel segment id map
    if (i == GH - 1) ws[is_row ? OFF_NROWS : OFF_NCOLS] = seg + 1;
}

// ---- Phase A: colsum[r][x][cq] = sum_{y in rowseg r} in[y][x][cq] ----
__global__ __launch_bounds__(256) void col_sum(const float4* __restrict__ in,
                                               float4* __restrict__ colsum,
                                               const int* __restrict__ ws) {
    const int N = ws[OFF_NROWS] * ROWQ;
    const int stride = gridDim.x * blockDim.x;   // multiple of 64
    for (int u = blockIdx.x * blockDim.x + threadIdx.x; u < N; u += stride) {
        const int r   = u / ROWQ;                // uniform across the wave
        const int rem = u - r * ROWQ;            // = x*16 + cq
        const int y0 = ws[OFF_ROWSTART + r];
        const int y1 = ws[OFF_ROWEND + r];
        float4 a0 = make_float4(0.f, 0.f, 0.f, 0.f);
        float4 a1 = make_float4(0.f, 0.f, 0.f, 0.f);
        int y = y0;
        for (; y + 1 < y1; y += 2) {
            acc4(a0, in[(size_t)y * ROWQ + rem]);
            acc4(a1, in[(size_t)(y + 1) * ROWQ + rem]);
        }
        if (y < y1) acc4(a0, in[(size_t)y * ROWQ + rem]);
        acc4(a0, a1);
        colsum[u] = a0;
    }
}

// ---- Phase B: mean[r][s][cq] = (sum_{x in colseg s} colsum[r][x][cq]) / area ----
__global__ __launch_bounds__(256) void cell_mean(const float4* __restrict__ colsum,
                                                 float4* __restrict__ mean,
                                                 const int* __restrict__ ws) {
    const int nrows = ws[OFF_NROWS];
    const int ncols = ws[OFF_NCOLS];
    const int N = nrows * ncols * 16;
    const int stride = gridDim.x * blockDim.x;
    for (int v = blockIdx.x * blockDim.x + threadIdx.x; v < N; v += stride) {
        const int cq = v & 15;
        const int rs = v >> 4;
        const int r  = rs / ncols;
        const int s  = rs - r * ncols;
        const int x0 = ws[OFF_COLSTART + s];
        const int x1 = ws[OFF_COLEND + s];
        float4 a = make_float4(0.f, 0.f, 0.f, 0.f);
        for (int x = x0; x < x1; ++x)
            acc4(a, colsum[(size_t)r * ROWQ + x * 16 + cq]);
        const float area =
            (float)((ws[OFF_ROWEND + r] - ws[OFF_ROWSTART + r]) * (x1 - x0));
        float4 mn;
        mn.x = a.x / area; mn.y = a.y / area; mn.z = a.z / area; mn.w = a.w / area;
        mean[v] = mn;
    }
}

// ---- Phase C: out[y][x][cq] = mean[rid[y]*ncols + cid[x]][cq] ----
__global__ __launch_bounds__(256) void bcast(const float4* __restrict__ mean,
                                             float4* __restrict__ out,
                                             const int* __restrict__ ws) {
    const int y  = blockIdx.y;
    const int id = blockIdx.x * 256 + threadIdx.x;   // in [0, 12288)
    const int x  = id >> 4;
    const int cq = id & 15;
    const int rid = ws[OFF_RID + y];                 // uniform per block
    const int cid = ws[OFF_CID + x];
    const int ncols = ws[OFF_NCOLS];
    out[(size_t)y * ROWQ + id] = mean[((size_t)rid * ncols + cid) * 16 + cq];
}

// ---- Fallback: R2 static wave-per-cell (used only if ws too small) ----
__global__ __launch_bounds__(256) void cell_pool(const float4* __restrict__ in,
                                                 float4* __restrict__ out,
                                                 const int* __restrict__ ws) {
    const int nrows  = ws[OFF_NROWS];
    const int ncols  = ws[OFF_NCOLS];
    const int ncells = nrows * ncols;

    const int wave   = blockIdx.x * 4 + (threadIdx.x >> 6);
    const int nwaves = gridDim.x * 4;
    const int lane   = threadIdx.x & 63;
    const int pg     = lane >> 4;
    const int cq     = lane & 15;

    for (int cell = wave; cell < ncells; cell += nwaves) {
        const int br = cell / ncols;
        const int bc = cell - br * ncols;
        const int y0 = ws[OFF_ROWSTART + br];
        const int y1 = ws[OFF_ROWEND + br];
        const int x0 = ws[OFF_COLSTART + bc];
        const int x1 = ws[OFF_COLEND + bc];

        float4 a = make_float4(0.f, 0.f, 0.f, 0.f);
        for (int y = y0; y < y1; ++y) {
            const size_t rb = (size_t)y * ROWQ + cq;
            for (int x = x0 + pg; x < x1; x += 4)
                acc4(a, in[rb + (size_t)x * 16]);
        }
        #pragma unroll
        for (int msk = 16; msk < 64; msk <<= 1) {
            a.x += __shfl_xor(a.x, msk, 64);
            a.y += __shfl_xor(a.y, msk, 64);
            a.z += __shfl_xor(a.z, msk, 64);
            a.w += __shfl_xor(a.w, msk, 64);
        }
        const float area = (float)((y1 - y0) * (x1 - x0));
        float4 mn;
        mn.x = a.x / area; mn.y = a.y / area; mn.z = a.z / area; mn.w = a.w / area;
        for (int y = y0; y < y1; ++y) {
            const size_t rb = (size_t)y * ROWQ + cq;
            for (int x = x0 + pg; x < x1; x += 4)
                out[rb + (size_t)x * 16] = mn;
        }
    }
}

extern "C" void kernel_launch(void* const* d_in, const int* in_sizes, int n_in,
                              void* d_out, int out_size, void* d_ws, size_t ws_size,
                              hipStream_t stream) {
    const float* in  = (const float*)d_in[0];   // [1,768,768,64] fp32
    const int* hmask = (const int*)d_in[1];     // [1,768] int32
    const int* vmask = (const int*)d_in[2];     // [1,768] int32
    float* out = (float*)d_out;                 // [1,768,768,64] fp32
    int* ws = (int*)d_ws;

    seg_scan<<<2, GH, 0, stream>>>(hmask, vmask, ws);

    if (ws_size >= MEAN_OFF_BYTES + MEAN_CAP_BYTES) {
        float4* colsum = (float4*)d_out;  // scratch; overwritten by bcast later
        float4* mean   = (float4*)((char*)d_ws + MEAN_OFF_BYTES);
        col_sum<<<4096, 256, 0, stream>>>((const float4*)in, colsum, ws);
        cell_mean<<<2048, 256, 0, stream>>>(colsum, mean, ws);
        dim3 cgrid(GW * 16 / 256, GH);    // (48, 768)
        bcast<<<cgrid, 256, 0, stream>>>(mean, (float4*)out, ws);
    } else {
        cell_pool<<<2048, 256, 0, stream>>>((const float4*)in, (float4*)out, ws);
    }
}